// Round 2
// baseline (2688.068 us; speedup 1.0000x reference)
//
// Fused 2-layer GRU + classifier head, MI355X gfx950.
// B=2048, T=1024, D=64, H=32. Inputs/outputs FLOAT32; bf16 MFMA internally.
//
// Design (round 2):
//  - 128 blocks x 64 threads (1 wave). Each wave owns 16 batch rows, runs all
//    1024 timesteps for BOTH layers; h0/h1 live in registers. No LDS.
//  - MFMA: D[gate][batch] = W' @ h^T (M=96 gates as 6 16-row tiles, N=16
//    batch, K=32/64), mfma_f32_16x16x32_bf16, fp32 accumulate.
//  - rho row-permutation rho(16*tau+4*q+r)=8q+4*tau+r: the z/n tiles' C/D
//    registers land exactly in B-operand layout for the next step's hidden
//    matvec -> zero cross-lane movement per step.
//  - Pre-scaling: r,z rows * -log2(e) -> sigmoid = rcp(1+exp2(acc));
//                 n rows  * 2*log2(e) -> tanh    = 1-2*rcp(1+exp2(acc)).
//    fp32 biases folded into MFMA C-init fragments (free).
//  - x loaded fp32 (4x float4/lane/step), converted to bf16 fragments,
//    prefetched 1 step ahead (off the recurrence critical path).

#include <hip/hip_runtime.h>

#define B_ 2048
#define T_ 1024

typedef short short8 __attribute__((ext_vector_type(8)));
typedef float floatx4 __attribute__((ext_vector_type(4)));

#define MFMA16(a, b, c) __builtin_amdgcn_mfma_f32_16x16x32_bf16((a), (b), (c), 0, 0, 0)
#define NLOG2E -1.4426950408889634f
#define TWOLOG2E 2.8853900817779268f

__device__ __forceinline__ unsigned short f2bf(float f) {
  union { float f; unsigned int i; } v;
  v.f = f;
  unsigned int r = v.i + 0x7fffu + ((v.i >> 16) & 1u);  // RNE
  return (unsigned short)(r >> 16);
}
__device__ __forceinline__ unsigned int pack2(float lo, float hi) {
  return ((unsigned int)f2bf(hi) << 16) | (unsigned int)f2bf(lo);
}

// position within a 32-row gate block -> logical (torch) row index
__device__ __forceinline__ int rho32(int pb) {
  return 8 * ((pb >> 2) & 3) + 4 * (pb >> 4) + (pb & 3);
}

// A-operand fragment of permuted+prescaled weight matrix W' (96 x K), fp32 src.
// A[m=lane&15][k=8*quad+j]; tile row m=c maps to torch row 32*blk+rho32(pb).
__device__ __forceinline__ short8 load_wfrag(const float* W, int K,
                                             int mt, int kt, int q, int c) {
  int p = 16 * mt + c;
  int blk = p >> 5;
  int pb = p & 31;
  int tr = 32 * blk + rho32(pb);
  float s = (blk < 2) ? NLOG2E : TWOLOG2E;
  const float* src = W + tr * K + 32 * kt + 8 * q;
  short8 out;
#pragma unroll
  for (int j = 0; j < 8; j++) out[j] = (short)f2bf(src[j] * s);
  return out;
}

// C-init fragment for r,z tiles (tau 0..3): -log2e*(b_ih+b_hh), permuted rows
__device__ __forceinline__ floatx4 bias_rz(const float* bih, const float* bhh,
                                           int tau, int q) {
  floatx4 f;
#pragma unroll
  for (int r = 0; r < 4; r++) {
    int p = 16 * tau + 4 * q + r;  // 0..63 across r,z blocks
    int idx = 32 * (p >> 5) + rho32(p & 31);
    f[r] = NLOG2E * (bih[idx] + bhh[idx]);
  }
  return f;
}
// C-init fragment for n tiles: 2*log2e * bias[64 + rho]
__device__ __forceinline__ floatx4 bias_n(const float* bias, int tau2, int q) {
  floatx4 f;
#pragma unroll
  for (int r = 0; r < 4; r++) {
    int pb = 16 * tau2 + 4 * q + r;
    f[r] = TWOLOG2E * bias[64 + rho32(pb)];
  }
  return f;
}

// 8 consecutive fp32 -> bf16 B-operand half-fragment
__device__ __forceinline__ short8 xfrag8(const float* p) {
  float4 a = *(const float4*)p;
  float4 b = *(const float4*)(p + 4);
  union { short8 s8; unsigned int u[4]; } P;
  P.u[0] = pack2(a.x, a.y);
  P.u[1] = pack2(a.z, a.w);
  P.u[2] = pack2(b.x, b.y);
  P.u[3] = pack2(b.z, b.w);
  return P.s8;
}

// GRU gate elementwise + h update + bf16 repack into B-operand fragment.
// arz[0..1]=r tiles (prescaled -log2e), arz[2..3]=z, anx/anh = n parts (2log2e).
// Register slot (t2, r) <-> per-lane h index j = 4*t2 + r (logical 8q+j).
__device__ __forceinline__ void gru_update(const floatx4* arz, const floatx4* anx,
                                           const floatx4* anh, float* h,
                                           short8* hf) {
#pragma unroll
  for (int t2 = 0; t2 < 2; t2++) {
#pragma unroll
    for (int r = 0; r < 4; r++) {
      float rr = __builtin_amdgcn_rcpf(1.0f + __builtin_amdgcn_exp2f(arz[t2][r]));
      float zz = __builtin_amdgcn_rcpf(1.0f + __builtin_amdgcn_exp2f(arz[2 + t2][r]));
      float u = fmaf(rr, anh[t2][r], anx[t2][r]);
      float nn = fmaf(-2.0f, __builtin_amdgcn_rcpf(1.0f + __builtin_amdgcn_exp2f(u)), 1.0f);
      int j = 4 * t2 + r;
      h[j] = fmaf(zz, h[j] - nn, nn);  // (1-z)*n + z*h
    }
  }
  union { short8 s8; unsigned int u[4]; } P;
#pragma unroll
  for (int k2 = 0; k2 < 4; k2++) P.u[k2] = pack2(h[2 * k2], h[2 * k2 + 1]);
  *hf = P.s8;
}

__global__ __launch_bounds__(64, 1) void gru_fused(
    const float* __restrict__ x,
    const float* __restrict__ wih0, const float* __restrict__ whh0,
    const float* __restrict__ bih0, const float* __restrict__ bhh0,
    const float* __restrict__ wih1, const float* __restrict__ whh1,
    const float* __restrict__ bih1, const float* __restrict__ bhh1,
    const float* __restrict__ wcls, const float* __restrict__ bcls,
    float* __restrict__ out) {
  const int lane = threadIdx.x & 63;
  const int q = lane >> 4;
  const int c = lane & 15;
  const int b = blockIdx.x * 16 + c;

  // ---- weight fragments (permuted + prescaled), held in registers ----
  short8 Aih0[6][2], Ahh0[6], Aih1[6], Ahh1[6];
#pragma unroll
  for (int mt = 0; mt < 6; mt++) {
    Aih0[mt][0] = load_wfrag(wih0, 64, mt, 0, q, c);
    Aih0[mt][1] = load_wfrag(wih0, 64, mt, 1, q, c);
    Ahh0[mt] = load_wfrag(whh0, 32, mt, 0, q, c);
    Aih1[mt] = load_wfrag(wih1, 32, mt, 0, q, c);
    Ahh1[mt] = load_wfrag(whh1, 32, mt, 0, q, c);
  }
  floatx4 brz0[4], brz1[4], bnx0[2], bnh0[2], bnx1[2], bnh1[2];
#pragma unroll
  for (int tau = 0; tau < 4; tau++) {
    brz0[tau] = bias_rz(bih0, bhh0, tau, q);
    brz1[tau] = bias_rz(bih1, bhh1, tau, q);
  }
#pragma unroll
  for (int t2 = 0; t2 < 2; t2++) {
    bnx0[t2] = bias_n(bih0, t2, q);
    bnh0[t2] = bias_n(bhh0, t2, q);
    bnx1[t2] = bias_n(bih1, t2, q);
    bnh1[t2] = bias_n(bhh1, t2, q);
  }
  float wc[8];
#pragma unroll
  for (int j = 0; j < 8; j++) wc[j] = wcls[8 * q + j];

  // ---- state ----
  float h0[8], h1[8];
  short8 h0f, h1f;
#pragma unroll
  for (int j = 0; j < 8; j++) {
    h0[j] = 0.f;
    h1[j] = 0.f;
    h0f[j] = 0;
    h1f[j] = 0;
  }

  // x B-fragment: lane(q,c) reads x[b][t][32*kt + 8q .. +7], fp32
  const float* px = x + ((size_t)b * T_) * 64 + 8 * q;
  short8 xc0 = xfrag8(px);
  short8 xc1 = xfrag8(px + 32);

  floatx4 arz[4], anx[2], anh[2];

  for (int t = 0; t < T_; ++t) {
    const int tn = (t + 1 < T_) ? (t + 1) : t;
    short8 xn0 = xfrag8(px + (size_t)tn * 64);
    short8 xn1 = xfrag8(px + (size_t)tn * 64 + 32);

    // ---- layer 0: gates = Wih0'@x_t + Whh0'@h0 (+bias via C-init) ----
#pragma unroll
    for (int tau = 0; tau < 4; tau++) {
      floatx4 a = MFMA16(Aih0[tau][0], xc0, brz0[tau]);
      a = MFMA16(Aih0[tau][1], xc1, a);
      arz[tau] = MFMA16(Ahh0[tau], h0f, a);
    }
#pragma unroll
    for (int t2 = 0; t2 < 2; t2++) {
      floatx4 a = MFMA16(Aih0[4 + t2][0], xc0, bnx0[t2]);
      anx[t2] = MFMA16(Aih0[4 + t2][1], xc1, a);
      anh[t2] = MFMA16(Ahh0[4 + t2], h0f, bnh0[t2]);
    }
    gru_update(arz, anx, anh, h0, &h0f);

    // ---- layer 1: input is h0f ----
#pragma unroll
    for (int tau = 0; tau < 4; tau++) {
      floatx4 a = MFMA16(Aih1[tau], h0f, brz1[tau]);
      arz[tau] = MFMA16(Ahh1[tau], h1f, a);
    }
#pragma unroll
    for (int t2 = 0; t2 < 2; t2++) {
      anx[t2] = MFMA16(Aih1[4 + t2], h0f, bnx1[t2]);
      anh[t2] = MFMA16(Ahh1[4 + t2], h1f, bnh1[t2]);
    }
    gru_update(arz, anx, anh, h1, &h1f);

    xc0 = xn0;
    xc1 = xn1;
  }

  // ---- outputs (fp32): y[2048], hidden[2][2048][32], h logical k=8q+j ----
  float* oh0 = out + 2048 + (size_t)b * 32 + 8 * q;
  float* oh1 = oh0 + 65536;
  *(float4*)oh0 = make_float4(h0[0], h0[1], h0[2], h0[3]);
  *(float4*)(oh0 + 4) = make_float4(h0[4], h0[5], h0[6], h0[7]);
  *(float4*)oh1 = make_float4(h1[0], h1[1], h1[2], h1[3]);
  *(float4*)(oh1 + 4) = make_float4(h1[4], h1[5], h1[6], h1[7]);

  float acc = 0.f;
#pragma unroll
  for (int j = 0; j < 8; j++) acc = fmaf(h1[j], wc[j], acc);
  acc += __shfl_xor(acc, 16, 64);
  acc += __shfl_xor(acc, 32, 64);
  if (q == 0) {
    float pre = acc + bcls[0];
    out[b] = __builtin_amdgcn_rcpf(1.0f + __builtin_amdgcn_exp2f(NLOG2E * pre));
  }
}

extern "C" void kernel_launch(void* const* d_in, const int* in_sizes, int n_in,
                              void* d_out, int out_size, void* d_ws, size_t ws_size,
                              hipStream_t stream) {
  const float* x    = (const float*)d_in[0];
  const float* wih0 = (const float*)d_in[1];
  const float* whh0 = (const float*)d_in[2];
  const float* bih0 = (const float*)d_in[3];
  const float* bhh0 = (const float*)d_in[4];
  const float* wih1 = (const float*)d_in[5];
  const float* whh1 = (const float*)d_in[6];
  const float* bih1 = (const float*)d_in[7];
  const float* bhh1 = (const float*)d_in[8];
  const float* wcls = (const float*)d_in[9];
  const float* bcls = (const float*)d_in[10];
  float* out = (float*)d_out;

  gru_fused<<<dim3(B_ / 16), dim3(64), 0, stream>>>(
      x, wih0, whh0, bih0, bhh0, wih1, whh1, bih1, bhh1, wcls, bcls, out);
}